// Round 1
// 101.260 us; speedup vs baseline: 1.0019x; 1.0019x over previous
//
#include <hip/hip_runtime.h>
#include <hip/hip_fp16.h>

#define HH 128
#define WW 128
#define CC 64
#define OO 64
#define HWSZ (HH*WW)

typedef _Float16 f16x8 __attribute__((ext_vector_type(8)));
typedef float    f32x4 __attribute__((ext_vector_type(4)));

__device__ __forceinline__ unsigned short f2h(float f) {
    return __half_as_ushort(__float2half_rn(f));
}

// ---------------------------------------------------------------------------
// K0: prep_all. z<4: x NCHW fp32 -> NHWC fp16 (LDS-tiled transpose).
//     z==4: weight repack -> fp16 in MFMA B-fragment-major order (16x16x32):
//       wdtf[kc(18)][nt(4)][lane(64)][j(8)] : o=nt*16+(l&15), c=(kc&1)*32+((l>>4)&3)*8+j, k=kc>>1
//       wotf[kc(18)][nt(2)][lane(64)][j(8)] : same, oc>=18 zero-padded
// ---------------------------------------------------------------------------
__global__ __launch_bounds__(256) void prep_all(const float* __restrict__ x,
                                                const float* __restrict__ wd,
                                                const float* __restrict__ wo,
                                                unsigned short* __restrict__ xh,
                                                unsigned short* __restrict__ wdtf,
                                                unsigned short* __restrict__ wotf) {
    int t = threadIdx.x;
    if (blockIdx.z == 4) {
        int i = (blockIdx.y * 2 + blockIdx.x) * 256 + t;
        if (i < 36864) {
            int j = i & 7, l = (i >> 3) & 63, nt = (i >> 9) & 3, kcb = i >> 11;
            int k = kcb >> 1, cb = kcb & 1;
            int o = nt * 16 + (l & 15);
            int c = cb * 32 + ((l >> 4) & 3) * 8 + j;
            wdtf[i] = f2h(wd[(o * 64 + c) * 9 + k]);
        } else if (i < 36864 + 18432) {
            int jdx = i - 36864;
            int j = jdx & 7, l = (jdx >> 3) & 63, nt = (jdx >> 9) & 1, kcb = jdx >> 10;
            int k = kcb >> 1, cb = kcb & 1;
            int oc = nt * 16 + (l & 15);
            int c = cb * 32 + ((l >> 4) & 3) * 8 + j;
            wotf[jdx] = f2h(oc < 18 ? wo[(oc * 64 + c) * 9 + k] : 0.0f);
        }
        return;
    }
    __shared__ float tile[64 * 65];
    int w0 = blockIdx.x * 64, h = blockIdx.y, b = blockIdx.z;
    const float* xb = x + ((long)b * CC * HWSZ) + h * WW + w0;
#pragma unroll
    for (int i = 0; i < 16; ++i) {
        int idx = i * 256 + t; int c = idx >> 6, w = idx & 63;
        tile[c * 65 + w] = xb[c * HWSZ + w];
    }
    __syncthreads();
    unsigned short* xo = xh + ((long)((b * HH + h) * WW + w0)) * CC;
#pragma unroll
    for (int i = 0; i < 8; ++i) {
        int idx = i * 256 + t; int w = idx >> 5, c = (idx & 31) * 2;
        ushort2 u;
        u.x = f2h(tile[c * 65 + w]);
        u.y = f2h(tile[(c + 1) * 65 + w]);
        *(ushort2*)(xo + w * CC + c) = u;
    }
}

// ---------------------------------------------------------------------------
// K1: fused offset+deform conv.  R10: occupancy 3->4 blocks/CU.
//   LDS diet: K-split val_s [32][VST=328] (5k / 4k halves) so union is
//   dominated by xr (29.4KB); offs stride 18 f32 (4.6KB). Total 34.0KB.
//   Breg[18] dropped -> B-frags re-read from L2-hot wdtf inside MFMA loop
//   (frees 72 VGPRs for the 128-reg cap of __launch_bounds__(256,4)).
//   All 1024 blocks co-resident: no 256-block tail round, 16 waves/CU to
//   hide gather latency.  s_setprio(1) around MFMA (blocks at different
//   phases per CU -> scheduler has work to arbitrate).
// LDS: union(xr 29.4KB, val_s 21.0KB) + offs 4.6KB = 34.0KB -> 4 blocks/CU.
// ---------------------------------------------------------------------------
#define VST 328   // val_s row stride (ushorts): 5*64 + 8 pad; word-stride 164 % 32 == 4 -> balanced banks
#define OST 18    // offs row stride (floats): write 2-way uniform, read distinct banks

template<int K0, int KN>
__device__ __forceinline__ void sample_seg(const unsigned short* __restrict__ xb,
                                           const float* __restrict__ oprow,
                                           unsigned short* __restrict__ val_s,
                                           int h, int wpx, int spx, int ch8) {
#pragma unroll
    for (int k = K0; k < K0 + KN; ++k) {
        int ky = k / 3, kx = k - ky * 3;
        float2 ov = *(const float2*)(oprow + 2 * k);
        float py  = (float)(h + ky - 1) + ov.x;
        float pxf = (float)(wpx + kx - 1) + ov.y;
        float y0f = floorf(py), x0f = floorf(pxf);
        float wy = py - y0f, wx = pxf - x0f;
        int y0 = (int)y0f, x0 = (int)x0f, y1 = y0 + 1, x1 = x0 + 1;
        bool vy0 = (unsigned)y0 < HH, vy1 = (unsigned)y1 < HH;
        bool vx0 = (unsigned)x0 < WW, vx1 = (unsigned)x1 < WW;
        int y0c = min(max(y0, 0), HH - 1), y1c = min(max(y1, 0), HH - 1);
        int x0c = min(max(x0, 0), WW - 1), x1c = min(max(x1, 0), WW - 1);
        _Float16 h0w = (_Float16)((vy0 && vx0) ? (1.f - wy) * (1.f - wx) : 0.f);
        _Float16 h1w = (_Float16)((vy0 && vx1) ? (1.f - wy) * wx : 0.f);
        _Float16 h2w = (_Float16)((vy1 && vx0) ? wy * (1.f - wx) : 0.f);
        _Float16 h3w = (_Float16)((vy1 && vx1) ? wy * wx : 0.f);
        f16x8 s00 = *(const f16x8*)(xb + (y0c * WW + x0c) * CC + ch8);
        f16x8 s01 = *(const f16x8*)(xb + (y0c * WW + x1c) * CC + ch8);
        f16x8 s10 = *(const f16x8*)(xb + (y1c * WW + x0c) * CC + ch8);
        f16x8 s11 = *(const f16x8*)(xb + (y1c * WW + x1c) * CC + ch8);
        f16x8 a = s00 * h0w + s01 * h1w + s10 * h2w + s11 * h3w;  // v_pk_fma_f16
        *(f16x8*)&val_s[spx * VST + (k - K0) * 64 + ch8] = a;
    }
}

template<int K0, int KN>
__device__ __forceinline__ void mfma_seg(const unsigned short* __restrict__ val_s,
                                         const unsigned short* __restrict__ wdtf,
                                         int m, int q, int wv, int l,
                                         f32x4& acc0, f32x4& acc1) {
#pragma unroll
    for (int ki = 0; ki < KN; ++ki) {
        const unsigned short* vs = &val_s[m * VST + ki * 64 + q * 8];
        f16x8 a00 = *(const f16x8*)(vs);
        f16x8 a01 = *(const f16x8*)(vs + 32);
        f16x8 a10 = *(const f16x8*)(vs + 16 * VST);
        f16x8 a11 = *(const f16x8*)(vs + 16 * VST + 32);
        int kcg = (K0 + ki) * 2;
        f16x8 b0 = *(const f16x8*)(wdtf + (kcg * 4 + wv) * 512 + l * 8);
        f16x8 b1 = *(const f16x8*)(wdtf + ((kcg + 1) * 4 + wv) * 512 + l * 8);
        acc0 = __builtin_amdgcn_mfma_f32_16x16x32_f16(a00, b0, acc0, 0, 0, 0);
        acc1 = __builtin_amdgcn_mfma_f32_16x16x32_f16(a10, b0, acc1, 0, 0, 0);
        acc0 = __builtin_amdgcn_mfma_f32_16x16x32_f16(a01, b1, acc0, 0, 0, 0);
        acc1 = __builtin_amdgcn_mfma_f32_16x16x32_f16(a11, b1, acc1, 0, 0, 0);
    }
}

__global__ __launch_bounds__(256, 4) void fused_dcn(const unsigned short* __restrict__ xh,
                                                    const unsigned short* __restrict__ wotf,
                                                    const float* __restrict__ b_off,
                                                    const unsigned short* __restrict__ wdtf,
                                                    const float* __restrict__ b_dcn,
                                                    float* __restrict__ out) {
    __shared__ __attribute__((aligned(16))) unsigned short shm[3 * 68 * 72]; // union: xr 29376B >= val_s 20992B
    __shared__ __attribute__((aligned(16))) float offs[64 * OST];
    unsigned short* xr    = shm;   // phase A: [row(3)][px(66,pad68)][ch(64,pad72)]
    unsigned short* val_s = shm;   // phase B: [px(32)][Kseg(320,pad328)]

    // ---- XCD-locality decode ----
    int id = blockIdx.x;
    int c8 = id & 7;           // XCD class
    int j  = id >> 3;
    int g  = (j >> 5) * 8 + c8;        // group 0..31 = b*8 + (h>>4)
    int inner = j & 31;
    int b  = g >> 3;
    int h  = (g & 7) * 16 + (inner >> 1);
    int w0 = (inner & 1) * 64;

    int t = threadIdx.x;
    int l = t & 63, wv = t >> 6;
    int m = l & 15, q = l >> 4;

    // ================= phase A: offset conv =================
#pragma unroll
    for (int i = 0; i < 7; ++i) {
        int idx = i * 256 + t;
        if (idx < 1584) {
            int r = idx / 528;
            int rem = idx - r * 528;
            int p = rem >> 3, cc = rem & 7;
            int y = h + r - 1, wx = w0 - 1 + p;
            uint4 v = make_uint4(0u, 0u, 0u, 0u);
            if (((unsigned)y < HH) && ((unsigned)wx < WW))
                v = *(const uint4*)(xh + ((long)((b * HH + y) * WW + wx)) * CC + cc * 8);
            *(uint4*)&xr[(r * 68 + p) * 72 + cc * 8] = v;
        }
    }
    __syncthreads();
    {
        int px0 = wv * 16;
        f32x4 acc0 = {0.f, 0.f, 0.f, 0.f}, acc1 = {0.f, 0.f, 0.f, 0.f};
#pragma unroll
        for (int k = 0; k < 9; ++k) {
            int ky = k / 3, kx = k - ky * 3;
            const unsigned short* ar = &xr[(ky * 68 + px0 + m + kx) * 72 + q * 8];
            f16x8 a0 = *(const f16x8*)(ar);
            f16x8 a1 = *(const f16x8*)(ar + 32);
            const unsigned short* bk = wotf + (k * 2) * 2 * 512 + l * 8;
            f16x8 b00 = *(const f16x8*)(bk);
            f16x8 b01 = *(const f16x8*)(bk + 512);
            f16x8 b10 = *(const f16x8*)(bk + 1024);
            f16x8 b11 = *(const f16x8*)(bk + 1536);
            acc0 = __builtin_amdgcn_mfma_f32_16x16x32_f16(a0, b00, acc0, 0, 0, 0);
            acc0 = __builtin_amdgcn_mfma_f32_16x16x32_f16(a1, b10, acc0, 0, 0, 0);
            acc1 = __builtin_amdgcn_mfma_f32_16x16x32_f16(a0, b01, acc1, 0, 0, 0);
            acc1 = __builtin_amdgcn_mfma_f32_16x16x32_f16(a1, b11, acc1, 0, 0, 0);
        }
        float bo0 = b_off[m];
#pragma unroll
        for (int r = 0; r < 4; ++r)
            offs[(px0 + q * 4 + r) * OST + m] = acc0[r] + bo0;
        if (m < 2) {
            float bo1 = b_off[16 + m];
#pragma unroll
            for (int r = 0; r < 4; ++r)
                offs[(px0 + q * 4 + r) * OST + 16 + m] = acc1[r] + bo1;
        }
    }
    __syncthreads();   // offs ready; xr dead; val_s may now overwrite shm

    // ================= phase B: deform conv (K-split 5+4) =================
    int spx = t >> 3, ch8 = (t & 7) * 8;    // sampler: pixel 0..31, 16B chunk

    const unsigned short* xb = xh + (long)b * HWSZ * CC;
    int o = wv * 16 + m;
    float bo = b_dcn[o];
    float* outo = out + ((long)(b * OO + o)) * HWSZ + h * WW;

#pragma unroll
    for (int g2 = 0; g2 < 2; ++g2) {
        int wg0 = w0 + g2 * 32;
        const float* oprow = &offs[(g2 * 32 + spx) * OST];
        int wpx = wg0 + spx;

        f32x4 acc0 = {0.f, 0.f, 0.f, 0.f}, acc1 = {0.f, 0.f, 0.f, 0.f};

        // ---- k = 0..4 ----
        sample_seg<0, 5>(xb, oprow, val_s, h, wpx, spx, ch8);
        __syncthreads();
        __builtin_amdgcn_s_setprio(1);
        mfma_seg<0, 5>(val_s, wdtf, m, q, wv, l, acc0, acc1);
        __builtin_amdgcn_s_setprio(0);
        __syncthreads();                       // WAR fence before refill

        // ---- k = 5..8 ----
        sample_seg<5, 4>(xb, oprow, val_s, h, wpx, spx, ch8);
        __syncthreads();
        __builtin_amdgcn_s_setprio(1);
        mfma_seg<5, 4>(val_s, wdtf, m, q, wv, l, acc0, acc1);
        __builtin_amdgcn_s_setprio(0);

        f32x4 r0 = acc0, r1 = acc1;
        r0[0] += bo; r0[1] += bo; r0[2] += bo; r0[3] += bo;
        r1[0] += bo; r1[1] += bo; r1[2] += bo; r1[3] += bo;
        *(f32x4*)(outo + wg0 + q * 4) = r0;
        *(f32x4*)(outo + wg0 + 16 + q * 4) = r1;
        if (g2 == 0) __syncthreads();   // val_s reuse fence for next sub-tile
    }
}

// ---------------------------------------------------------------------------
extern "C" void kernel_launch(void* const* d_in, const int* in_sizes, int n_in,
                              void* d_out, int out_size, void* d_ws, size_t ws_size,
                              hipStream_t stream) {
    const float* x     = (const float*)d_in[0];
    const float* w_off = (const float*)d_in[1];
    const float* b_off = (const float*)d_in[2];
    const float* w_dcn = (const float*)d_in[3];
    const float* b_dcn = (const float*)d_in[4];
    float* out = (float*)d_out;

    char* ws = (char*)d_ws;
    unsigned short* xh   = (unsigned short*)ws;              //  8,388,608 B
    unsigned short* wdtf = (unsigned short*)(ws + 8388608);  //     73,728 B
    unsigned short* wotf = (unsigned short*)(ws + 8462336);  //     36,864 B

    hipLaunchKernelGGL(prep_all, dim3(2, 128, 5), dim3(256), 0, stream,
                       x, w_dcn, w_off, xh, wdtf, wotf);
    hipLaunchKernelGGL(fused_dcn, dim3(1024), dim3(256), 0, stream,
                       xh, wotf, b_off, wdtf, b_dcn, out);
}